// Round 1
// baseline (800.260 us; speedup 1.0000x reference)
//
#include <hip/hip_runtime.h>
#include <cstdint>
#include <cstddef>

#define B_ROWS 512
#define E_DIM  512
#define C_CLS  100000
#define NT     782            // ceil(100000/128)

#define S_SC    30.0f
#define M_MRG   0.35f
#define LAMBDA_ 0.01f
#define ALPHA_  0.5f
#define EPS_    1e-6f

#define BM 128
#define BN 128
#define BK 64
#define LPAD 8                // pad to 72 bf16 = 144 B row stride (16*9: keeps 16B align, uniform bank residues)

typedef __attribute__((ext_vector_type(8))) short bf16x8;
typedef __attribute__((ext_vector_type(4))) float f32x4;

static_assert((size_t)NT * BN >= C_CLS, "tile count");

// ---------------- ws layout (bytes) ----------------
constexpr size_t WS_PSUM  = 0;                                    // NT*512 f32 partial sumexp
constexpr size_t WS_PMAX  = WS_PSUM + (size_t)NT * B_ROWS * 4;    // NT*512 u32 partial max keys
constexpr size_t WS_CLOSS = WS_PMAX + (size_t)NT * B_ROWS * 4;    // 1 f32 center-loss accum
constexpr size_t WS_ZERO  = WS_CLOSS + 512;                       // memset [0, WS_ZERO)
constexpr size_t WS_EMBN  = WS_ZERO;                              // 512*512 bf16 normalized emb
constexpr size_t WS_IEN   = WS_EMBN + (size_t)B_ROWS * E_DIM * 2; // 512 f32 1/||e||
constexpr size_t WS_COSL  = WS_IEN + 2048;                        // 512 f32 cos at label (f32-exact)
constexpr size_t WS_CNT   = WS_COSL + 2048;                       // 512 f32 label counts
constexpr size_t WS_RSUM  = WS_CNT + 2048;                        // 512 f32 row sumexp (non-label)
constexpr size_t WS_RMAX  = WS_RSUM + 2048;                       // 512 f32 row max   (non-label)

// ---------------- helpers ----------------
__device__ __forceinline__ unsigned short f2bf(float f) {
    unsigned u = __float_as_uint(f);
    u += 0x7fffu + ((u >> 16) & 1u);            // round-to-nearest-even
    return (unsigned short)(u >> 16);
}
__device__ __forceinline__ unsigned fkey(float f) {   // monotonic float->uint (for atomicMax)
    unsigned u = __float_as_uint(f);
    return (u & 0x80000000u) ? ~u : (u | 0x80000000u);
}
__device__ __forceinline__ float unkey(unsigned k) {
    unsigned u = (k & 0x80000000u) ? (k ^ 0x80000000u) : ~k;
    return __uint_as_float(u);
}
__device__ __forceinline__ float waveReduceSum(float v) {
#pragma unroll
    for (int d = 1; d < 64; d <<= 1) v += __shfl_xor(v, d, 64);
    return v;
}
__device__ __forceinline__ unsigned waveReduceMax(unsigned v) {
#pragma unroll
    for (int d = 1; d < 64; d <<= 1) { unsigned o = __shfl_xor(v, d, 64); v = o > v ? o : v; }
    return v;
}
// 256-thread block sum, result broadcast to all threads
__device__ __forceinline__ float blockReduceSum256(float v, float* s4) {
    v = waveReduceSum(v);
    int w = threadIdx.x >> 6;
    if ((threadIdx.x & 63) == 0) s4[w] = v;
    __syncthreads();
    float r = s4[0] + s4[1] + s4[2] + s4[3];
    __syncthreads();
    return r;
}

// ---------------- kernels ----------------

// normalize embedding rows -> bf16, store 1/||e||
__global__ __launch_bounds__(256) void emb_prep(const float* __restrict__ emb,
                                                unsigned short* __restrict__ embn,
                                                float* __restrict__ ien) {
    __shared__ float s4[4];
    int b = blockIdx.x, t = threadIdx.x;
    float2 v = *(const float2*)(emb + (size_t)b * E_DIM + t * 2);
    float ss = blockReduceSum256(v.x * v.x + v.y * v.y, s4);
    float inv = 1.0f / sqrtf(ss);
    ushort2 o; o.x = f2bf(v.x * inv); o.y = f2bf(v.y * inv);
    *(ushort2*)(embn + (size_t)b * E_DIM + t * 2) = o;
    if (t == 0) ien[b] = inv;
}

// per-sample: f32-exact label cosine, label count, center-loss accum
__global__ __launch_bounds__(256) void label_stats(const float* __restrict__ emb,
                                                   const float* __restrict__ W,
                                                   const float* __restrict__ centers,
                                                   const int* __restrict__ label,
                                                   const float* __restrict__ ien,
                                                   float* __restrict__ cosl,
                                                   float* __restrict__ cntf,
                                                   float* __restrict__ closs) {
    __shared__ float s4[4];
    int b = blockIdx.x, t = threadIdx.x;
    int lab = label[b];
    float d = 0.f, wss = 0.f, sq = 0.f;
    for (int c = t; c < E_DIM; c += 256) {
        float e  = emb[(size_t)b * E_DIM + c];
        float w  = W[(size_t)lab * E_DIM + c];
        float ce = centers[(size_t)lab * E_DIM + c];
        d += e * w; wss += w * w;
        float df = e - ce; sq += df * df;
    }
    float cn = ((label[t] == lab) ? 1.f : 0.f) + ((label[t + 256] == lab) ? 1.f : 0.f);
    d   = blockReduceSum256(d, s4);
    wss = blockReduceSum256(wss, s4);
    sq  = blockReduceSum256(sq, s4);
    cn  = blockReduceSum256(cn, s4);
    if (t == 0) {
        cosl[b] = d * ien[b] / sqrtf(wss);
        cntf[b] = cn;
        atomicAdd(closs, sq);
    }
}

// fused GEMM: cos = emb_n . w / ||w||, with online (fixed-offset) softmax partials.
// grid (4 m-tiles, 782 n-tiles), 256 threads.
__global__ __launch_bounds__(256) void gemm_logits(const unsigned short* __restrict__ embn,
                                                   const float* __restrict__ W,
                                                   const int* __restrict__ label,
                                                   float* __restrict__ psum,
                                                   unsigned* __restrict__ pmax) {
    __shared__ __align__(16) unsigned short sA[BM][BK + LPAD];
    __shared__ __align__(16) unsigned short sB[BN][BK + LPAD];
    __shared__ int      sLab[BM];
    __shared__ float    sSum[BM];
    __shared__ unsigned sMax[BM];
    __shared__ float    sInvN[BN];

    const int tid = threadIdx.x;
    const int m0 = blockIdx.x * BM;
    const int n0 = blockIdx.y * BN;
    if (tid < BM) { sLab[tid] = label[m0 + tid]; sSum[tid] = 0.f; sMax[tid] = 0u; }

    const int lane = tid & 63;
    const int wave = tid >> 6;
    const int wm = wave >> 1, wn = wave & 1;
    const int q = lane >> 4, lm = lane & 15;

    const int arow = tid >> 3, ac8 = tid & 7;    // A staging: 32 rows x 8 col-chunks
    const int brow = tid >> 4, bc4 = tid & 15;   // B staging: 16 rows x 16 col-chunks

    f32x4 acc[4][4];
#pragma unroll
    for (int i = 0; i < 4; ++i)
#pragma unroll
        for (int j = 0; j < 4; ++j) acc[i][j] = (f32x4){0.f, 0.f, 0.f, 0.f};

    float rss[8];
#pragma unroll
    for (int j = 0; j < 8; ++j) rss[j] = 0.f;

    const float* wb = W + (size_t)(n0 + brow) * E_DIM + bc4 * 4;

    for (int k0 = 0; k0 < E_DIM; k0 += BK) {
        __syncthreads();
        // stage A (already bf16-normalized)
#pragma unroll
        for (int j = 0; j < 4; ++j) {
            int rr = arow + 32 * j;
            uint4 v = *(const uint4*)(embn + (size_t)(m0 + rr) * E_DIM + k0 + ac8 * 8);
            *(uint4*)(&sA[rr][ac8 * 8]) = v;
        }
        // stage B: raw f32 -> bf16, accumulate row sum-of-squares for the norm
#pragma unroll
        for (int j = 0; j < 8; ++j) {
            int rr = brow + 16 * j;
            f32x4 v = (f32x4){0.f, 0.f, 0.f, 0.f};
            if (n0 + rr < C_CLS) v = *(const f32x4*)(wb + (size_t)(16 * j) * E_DIM + k0);
            rss[j] += v.x * v.x + v.y * v.y + v.z * v.z + v.w * v.w;
            ushort4 o; o.x = f2bf(v.x); o.y = f2bf(v.y); o.z = f2bf(v.z); o.w = f2bf(v.w);
            *(ushort4*)(&sB[rr][bc4 * 4]) = o;
        }
        __syncthreads();
#pragma unroll
        for (int kk = 0; kk < BK; kk += 32) {
            bf16x8 af[4], bfr[4];
#pragma unroll
            for (int i = 0; i < 4; ++i)
                af[i] = *(const bf16x8*)(&sA[wm * 64 + i * 16 + lm][kk + q * 8]);
#pragma unroll
            for (int j = 0; j < 4; ++j)
                bfr[j] = *(const bf16x8*)(&sB[wn * 64 + j * 16 + lm][kk + q * 8]);
#pragma unroll
            for (int i = 0; i < 4; ++i)
#pragma unroll
                for (int j = 0; j < 4; ++j)
                    acc[i][j] = __builtin_amdgcn_mfma_f32_16x16x32_bf16(af[i], bfr[j], acc[i][j], 0, 0, 0);
        }
    }

    // finish weight-row inverse norms (reduce across the 16 bc4 lanes of each row)
#pragma unroll
    for (int j = 0; j < 8; ++j) {
        float v = rss[j];
#pragma unroll
        for (int d = 1; d < 16; d <<= 1) v += __shfl_xor(v, d, 64);
        if (bc4 == 0) sInvN[brow + 16 * j] = rsqrtf(fmaxf(v, 1e-30f));
    }
    __syncthreads();

    // epilogue: fixed-offset exp-sum and max over this 128x128 tile (label & OOB excluded)
#pragma unroll
    for (int i = 0; i < 4; ++i) {
#pragma unroll
        for (int r = 0; r < 4; ++r) {
            int row_l = wm * 64 + i * 16 + q * 4 + r;
            int lab = sLab[row_l];
            float sum = 0.f, mx = -1e30f;
#pragma unroll
            for (int j = 0; j < 4; ++j) {
                int col_l = wn * 64 + j * 16 + lm;
                int col = n0 + col_l;
                float v = S_SC * acc[i][j][r] * sInvN[col_l];
                if (col < C_CLS && col != lab) {
                    sum += __expf(v - 30.0f);      // m_logits <= ~30 by construction
                    mx = fmaxf(mx, v);
                }
            }
#pragma unroll
            for (int d = 1; d < 16; d <<= 1) {
                sum += __shfl_xor(sum, d, 64);
                mx = fmaxf(mx, __shfl_xor(mx, d, 64));
            }
            if (lm == 0) {
                atomicAdd(&sSum[row_l], sum);                 // 2 adds/addr: commutative -> deterministic
                atomicMax(&sMax[row_l], fkey(mx));
            }
        }
    }
    __syncthreads();
    if (tid < BM) {
        psum[(size_t)blockIdx.y * B_ROWS + m0 + tid] = sSum[tid];
        pmax[(size_t)blockIdx.y * B_ROWS + m0 + tid] = sMax[tid];
    }
}

// fixed-order reduction over the 782 tile-partials per row (deterministic)
__global__ __launch_bounds__(256) void row_reduce(const float* __restrict__ psum,
                                                  const unsigned* __restrict__ pmax,
                                                  float* __restrict__ rsum,
                                                  float* __restrict__ rmax) {
    __shared__ float s4[4];
    __shared__ unsigned m4[4];
    int b = blockIdx.x, t = threadIdx.x;
    float s = 0.f; unsigned mk = 0u;
    for (int nt = t; nt < NT; nt += 256) {
        s += psum[(size_t)nt * B_ROWS + b];
        unsigned k = pmax[(size_t)nt * B_ROWS + b];
        mk = k > mk ? k : mk;
    }
    s = waveReduceSum(s);
    mk = waveReduceMax(mk);
    int w = t >> 6;
    if ((t & 63) == 0) { s4[w] = s; m4[w] = mk; }
    __syncthreads();
    if (t == 0) {
        rsum[b] = s4[0] + s4[1] + s4[2] + s4[3];
        unsigned m = m4[0];
#pragma unroll
        for (int i = 1; i < 4; ++i) m = m4[i] > m ? m4[i] : m;
        rmax[b] = unkey(m);
    }
}

__global__ __launch_bounds__(256) void finalize(const float* __restrict__ cosl,
                                                const float* __restrict__ rsum,
                                                const float* __restrict__ rmax,
                                                const float* __restrict__ closs,
                                                float* __restrict__ out) {
    __shared__ float s4[4];
    int t = threadIdx.x;
    float lsum = 0.f, msum = 0.f;
    for (int b = t; b < B_ROWS; b += 256) {
        float lv = S_SC * (cosl[b] - M_MRG);                 // exact-f32 margined label logit
        float tot = rsum[b] + __expf(lv - 30.0f);            // merge label term into sumexp
        lsum += (logf(tot) + 30.0f) - lv;                    // -log_softmax at label
        msum += (lv > rmax[b]) ? 1.0f : 0.0f;                // argmax == label ?
    }
    lsum = blockReduceSum256(lsum, s4);
    msum = blockReduceSum256(msum, s4);
    if (t == 0) {
        out[0] = msum * (100.0f / (float)B_ROWS);
        out[1] = lsum * (1.0f / (float)B_ROWS)
               + LAMBDA_ * closs[0] * (1.0f / ((float)B_ROWS * (float)E_DIM));
    }
}

// new_centers = centers (bulk copy; dst is 8B-aligned so float2)
__global__ __launch_bounds__(256) void centers_copy(const float* __restrict__ src,
                                                    float* __restrict__ dst) {
    size_t i = (size_t)blockIdx.x * blockDim.x + threadIdx.x;
    size_t stride = (size_t)gridDim.x * blockDim.x;
    size_t n2 = (size_t)C_CLS * E_DIM / 2;
    const float2* s2 = (const float2*)src;
    float2* d2 = (float2*)dst;
    for (size_t k = i; k < n2; k += stride) d2[k] = s2[k];
}

// scatter: new_centers[label[b]] += alpha*(e - c)/(count+eps)   (atomic, handles dup labels)
__global__ __launch_bounds__(256) void scatter_upd(const float* __restrict__ emb,
                                                   const float* __restrict__ centers,
                                                   const int* __restrict__ label,
                                                   const float* __restrict__ cntf,
                                                   float* __restrict__ outC) {
    int b = blockIdx.x, t = threadIdx.x;
    int lab = label[b];
    float sc = ALPHA_ / (cntf[b] + EPS_);
    for (int c = t; c < E_DIM; c += 256) {
        float add = sc * (emb[(size_t)b * E_DIM + c] - centers[(size_t)lab * E_DIM + c]);
        atomicAdd(outC + (size_t)lab * E_DIM + c, add);
    }
}

// ---------------- launcher ----------------
extern "C" void kernel_launch(void* const* d_in, const int* in_sizes, int n_in,
                              void* d_out, int out_size, void* d_ws, size_t ws_size,
                              hipStream_t stream) {
    const float* emb     = (const float*)d_in[0];
    const float* W       = (const float*)d_in[1];
    const float* centers = (const float*)d_in[2];
    const int*   label   = (const int*)d_in[3];
    float* out = (float*)d_out;
    char* ws = (char*)d_ws;

    float*          psum = (float*)(ws + WS_PSUM);
    unsigned*       pmax = (unsigned*)(ws + WS_PMAX);
    float*          closs = (float*)(ws + WS_CLOSS);
    unsigned short* embn = (unsigned short*)(ws + WS_EMBN);
    float*          ien  = (float*)(ws + WS_IEN);
    float*          cosl = (float*)(ws + WS_COSL);
    float*          cntf = (float*)(ws + WS_CNT);
    float*          rsum = (float*)(ws + WS_RSUM);
    float*          rmax = (float*)(ws + WS_RMAX);

    hipMemsetAsync(ws, 0, WS_ZERO, stream);

    emb_prep<<<B_ROWS, 256, 0, stream>>>(emb, embn, ien);
    label_stats<<<B_ROWS, 256, 0, stream>>>(emb, W, centers, label, ien, cosl, cntf, closs);
    gemm_logits<<<dim3(B_ROWS / BM, NT), 256, 0, stream>>>(embn, W, label, psum, pmax);
    row_reduce<<<B_ROWS, 256, 0, stream>>>(psum, pmax, rsum, rmax);
    finalize<<<1, 256, 0, stream>>>(cosl, rsum, rmax, closs, out);
    centers_copy<<<12500, 256, 0, stream>>>(centers, out + 2);
    scatter_upd<<<B_ROWS, 256, 0, stream>>>(emb, centers, label, cntf, out + 2);
}

// Round 2
// 643.073 us; speedup vs baseline: 1.2444x; 1.2444x over previous
//
#include <hip/hip_runtime.h>
#include <cstdint>
#include <cstddef>

#define B_ROWS 512
#define E_DIM  512
#define C_CLS  100000
#define NT     782            // ceil(100000/128)

#define S_SC    30.0f
#define M_MRG   0.35f
#define LAMBDA_ 0.01f
#define ALPHA_  0.5f
#define EPS_    1e-6f

#define BM 128
#define BN 128
#define BK 64
#define LPAD 8                // fallback kernel only

typedef __attribute__((ext_vector_type(8))) short bf16x8;
typedef __attribute__((ext_vector_type(4))) float f32x4;

static_assert((size_t)NT * BN >= C_CLS, "tile count");

// ---------------- ws layout (bytes) ----------------
constexpr size_t WS_PSUM  = 0;                                    // NT*512 f32 partial sumexp
constexpr size_t WS_PMAX  = WS_PSUM + (size_t)NT * B_ROWS * 4;    // NT*512 u32 partial max keys
constexpr size_t WS_CLOSS = WS_PMAX + (size_t)NT * B_ROWS * 4;    // 1 f32 center-loss accum (zeroed region, 512 B)
constexpr size_t WS_EMBN  = WS_CLOSS + 512;                       // 512*512 bf16 normalized emb
constexpr size_t WS_IEN   = WS_EMBN + (size_t)B_ROWS * E_DIM * 2; // 512 f32 1/||e||
constexpr size_t WS_COSL  = WS_IEN + 2048;                        // 512 f32 cos at label (f32-exact)
constexpr size_t WS_CNT   = WS_COSL + 2048;                       // 512 f32 label counts
constexpr size_t WS_RSUM  = WS_CNT + 2048;                        // 512 f32 row sumexp (non-label)
constexpr size_t WS_RMAX  = WS_RSUM + 2048;                       // 512 f32 row max   (non-label)
constexpr size_t WS_WBF   = 4 * 1024 * 1024;                      // normalized bf16 W (fast path)
constexpr size_t WS_NEED  = WS_WBF + (size_t)C_CLS * E_DIM * 2;   // ~106.6 MB

// ---------------- helpers ----------------
__device__ __forceinline__ unsigned short f2bf(float f) {
    unsigned u = __float_as_uint(f);
    u += 0x7fffu + ((u >> 16) & 1u);            // round-to-nearest-even
    return (unsigned short)(u >> 16);
}
__device__ __forceinline__ unsigned fkey(float f) {   // monotonic float->uint (for atomicMax)
    unsigned u = __float_as_uint(f);
    return (u & 0x80000000u) ? ~u : (u | 0x80000000u);
}
__device__ __forceinline__ float unkey(unsigned k) {
    unsigned u = (k & 0x80000000u) ? (k ^ 0x80000000u) : ~k;
    return __uint_as_float(u);
}
__device__ __forceinline__ float waveReduceSum(float v) {
#pragma unroll
    for (int d = 1; d < 64; d <<= 1) v += __shfl_xor(v, d, 64);
    return v;
}
__device__ __forceinline__ unsigned waveReduceMax(unsigned v) {
#pragma unroll
    for (int d = 1; d < 64; d <<= 1) { unsigned o = __shfl_xor(v, d, 64); v = o > v ? o : v; }
    return v;
}
__device__ __forceinline__ float blockReduceSum256(float v, float* s4) {
    v = waveReduceSum(v);
    int w = threadIdx.x >> 6;
    if ((threadIdx.x & 63) == 0) s4[w] = v;
    __syncthreads();
    float r = s4[0] + s4[1] + s4[2] + s4[3];
    __syncthreads();
    return r;
}
// async global->LDS, 16 B per lane. LDS dest = wave-uniform base + lane*16.
__device__ __forceinline__ void g2l16(const void* g, void* l) {
    __builtin_amdgcn_global_load_lds(
        (const __attribute__((address_space(1))) unsigned int*)g,
        (__attribute__((address_space(3))) unsigned int*)l, 16, 0, 0);
}

// ---------------- kernels ----------------

// normalize embedding rows -> bf16, store 1/||e||
__global__ __launch_bounds__(256) void emb_prep(const float* __restrict__ emb,
                                                unsigned short* __restrict__ embn,
                                                float* __restrict__ ien) {
    __shared__ float s4[4];
    int b = blockIdx.x, t = threadIdx.x;
    float2 v = *(const float2*)(emb + (size_t)b * E_DIM + t * 2);
    float ss = blockReduceSum256(v.x * v.x + v.y * v.y, s4);
    float inv = 1.0f / sqrtf(ss);
    ushort2 o; o.x = f2bf(v.x * inv); o.y = f2bf(v.y * inv);
    *(ushort2*)(embn + (size_t)b * E_DIM + t * 2) = o;
    if (t == 0) ien[b] = inv;
}

// normalize classifier rows -> bf16 (one wave per row)
__global__ __launch_bounds__(256) void w_prep(const float* __restrict__ W,
                                              unsigned short* __restrict__ wbf) {
    int row = blockIdx.x * 4 + (threadIdx.x >> 6);
    int lane = threadIdx.x & 63;
    const float* src = W + (size_t)row * E_DIM;
    f32x4 a = *(const f32x4*)(src + lane * 4);
    f32x4 b = *(const f32x4*)(src + 256 + lane * 4);
    float ss = a.x*a.x + a.y*a.y + a.z*a.z + a.w*a.w
             + b.x*b.x + b.y*b.y + b.z*b.z + b.w*b.w;
    ss = waveReduceSum(ss);
    float inv = 1.0f / sqrtf(fmaxf(ss, 1e-30f));
    ushort4 o0, o1;
    o0.x = f2bf(a.x*inv); o0.y = f2bf(a.y*inv); o0.z = f2bf(a.z*inv); o0.w = f2bf(a.w*inv);
    o1.x = f2bf(b.x*inv); o1.y = f2bf(b.y*inv); o1.z = f2bf(b.z*inv); o1.w = f2bf(b.w*inv);
    *(ushort4*)(wbf + (size_t)row * E_DIM + lane * 4) = o0;
    *(ushort4*)(wbf + (size_t)row * E_DIM + 256 + lane * 4) = o1;
}

// per-sample: f32-exact label cosine, label count, center-loss accum
__global__ __launch_bounds__(256) void label_stats(const float* __restrict__ emb,
                                                   const float* __restrict__ W,
                                                   const float* __restrict__ centers,
                                                   const int* __restrict__ label,
                                                   const float* __restrict__ ien,
                                                   float* __restrict__ cosl,
                                                   float* __restrict__ cntf,
                                                   float* __restrict__ closs) {
    __shared__ float s4[4];
    int b = blockIdx.x, t = threadIdx.x;
    int lab = label[b];
    float d = 0.f, wss = 0.f, sq = 0.f;
    for (int c = t; c < E_DIM; c += 256) {
        float e  = emb[(size_t)b * E_DIM + c];
        float w  = W[(size_t)lab * E_DIM + c];
        float ce = centers[(size_t)lab * E_DIM + c];
        d += e * w; wss += w * w;
        float df = e - ce; sq += df * df;
    }
    float cn = ((label[t] == lab) ? 1.f : 0.f) + ((label[t + 256] == lab) ? 1.f : 0.f);
    d   = blockReduceSum256(d, s4);
    wss = blockReduceSum256(wss, s4);
    sq  = blockReduceSum256(sq, s4);
    cn  = blockReduceSum256(cn, s4);
    if (t == 0) {
        cosl[b] = d * ien[b] / sqrtf(wss);
        cntf[b] = cn;
        atomicAdd(closs, sq);
    }
}

// ---------- fast GEMM: one block per n-tile, m-loop inside, global_load_lds + XOR swizzle ----------
// LDS layout: tile = 128 rows x 64 bf16, flat. Granule = 8 bf16 (16 B).
// phys granule p of row r holds logical k-granule l = p ^ (r&7)  (bank-balanced reads).
__global__ __launch_bounds__(256) void gemm_fast(const unsigned short* __restrict__ embn,
                                                 const unsigned short* __restrict__ wbf,
                                                 const int* __restrict__ label,
                                                 float* __restrict__ psum,
                                                 unsigned* __restrict__ pmax) {
    __shared__ __align__(16) unsigned short sA[BM * BK];
    __shared__ __align__(16) unsigned short sB[BN * BK];
    __shared__ int      sLab[BM];
    __shared__ float    sSum[BM];
    __shared__ unsigned sMax[BM];

    const int tid = threadIdx.x;
    const int n0 = blockIdx.x * BN;
    const int lane = tid & 63, wave = tid >> 6;
    const int wm = wave >> 1, wn = wave & 1;
    const int q = lane >> 4, lm = lane & 15;
    const int lm7 = lm & 7;

    // staging descriptors: round j covers granules [j*256+wave*64, +64), lane l -> granule j*256+wave*64+l
    int aOff[4];                       // row*E + l*8 (add m-base + k0 later)
    const unsigned short* bP[4];       // wbf row ptr + l*8 (add k0 later)
    unsigned short *aD[4], *bD[4];
#pragma unroll
    for (int j = 0; j < 4; ++j) {
        int G = j * 256 + tid;
        int r = G >> 3, p = G & 7, l = p ^ (r & 7);
        aOff[j] = r * E_DIM + l * 8;
        int rg = n0 + r; if (rg >= C_CLS) rg = 0;          // clamp OOB rows (excluded in epilogue)
        bP[j] = wbf + (size_t)rg * E_DIM + l * 8;
        aD[j] = &sA[(j * 256 + wave * 64) * 8];
        bD[j] = &sB[(j * 256 + wave * 64) * 8];
    }

    for (int m = 0; m < 4; ++m) {
        if (tid < BM) { sLab[tid] = label[m * BM + tid]; sSum[tid] = 0.f; sMax[tid] = 0u; }
        const unsigned short* aBase = embn + (size_t)m * BM * E_DIM;

        f32x4 acc[4][4];
#pragma unroll
        for (int i = 0; i < 4; ++i)
#pragma unroll
            for (int j = 0; j < 4; ++j) acc[i][j] = (f32x4){0.f, 0.f, 0.f, 0.f};

        for (int k0 = 0; k0 < E_DIM; k0 += BK) {
            __syncthreads();                      // prior reads of sA/sB done
#pragma unroll
            for (int j = 0; j < 4; ++j) g2l16(aBase + aOff[j] + k0, aD[j]);
#pragma unroll
            for (int j = 0; j < 4; ++j) g2l16(bP[j] + k0, bD[j]);
            __syncthreads();                      // vmcnt(0) drained before barrier
#pragma unroll
            for (int kk = 0; kk < BK; kk += 32) {
                const int pg = ((kk >> 3) + q) ^ lm7;       // swizzled phys granule
                bf16x8 af[4], bfr[4];
#pragma unroll
                for (int i = 0; i < 4; ++i)
                    af[i] = *(const bf16x8*)&sA[(wm * 64 + i * 16 + lm) * BK + pg * 8];
#pragma unroll
                for (int j = 0; j < 4; ++j)
                    bfr[j] = *(const bf16x8*)&sB[(wn * 64 + j * 16 + lm) * BK + pg * 8];
#pragma unroll
                for (int i = 0; i < 4; ++i)
#pragma unroll
                    for (int j = 0; j < 4; ++j)
                        acc[i][j] = __builtin_amdgcn_mfma_f32_16x16x32_bf16(af[i], bfr[j], acc[i][j], 0, 0, 0);
            }
        }

        // epilogue: fixed-offset exp-sum and max over this 128x128 tile (label & OOB excluded)
#pragma unroll
        for (int i = 0; i < 4; ++i) {
#pragma unroll
            for (int r = 0; r < 4; ++r) {
                int row_l = wm * 64 + i * 16 + q * 4 + r;
                int lab = sLab[row_l];
                float sum = 0.f, mx = -1e30f;
#pragma unroll
                for (int j = 0; j < 4; ++j) {
                    int col_l = wn * 64 + j * 16 + lm;
                    int col = n0 + col_l;
                    float v = S_SC * acc[i][j][r];
                    if (col < C_CLS && col != lab) {
                        sum += __expf(v - 30.0f);          // m_logits <= ~30 by construction
                        mx = fmaxf(mx, v);
                    }
                }
#pragma unroll
                for (int d = 1; d < 16; d <<= 1) {
                    sum += __shfl_xor(sum, d, 64);
                    mx = fmaxf(mx, __shfl_xor(mx, d, 64));
                }
                if (lm == 0) {
                    atomicAdd(&sSum[row_l], sum);          // 2 adds/addr: commutative -> deterministic
                    atomicMax(&sMax[row_l], fkey(mx));
                }
            }
        }
        __syncthreads();
        if (tid < BM) {
            psum[(size_t)blockIdx.x * B_ROWS + m * BM + tid] = sSum[tid];
            pmax[(size_t)blockIdx.x * B_ROWS + m * BM + tid] = sMax[tid];
        }
    }
}

// ---------- fallback GEMM (round-1, used only if ws too small for wbf) ----------
__global__ __launch_bounds__(256) void gemm_slow(const unsigned short* __restrict__ embn,
                                                 const float* __restrict__ W,
                                                 const int* __restrict__ label,
                                                 float* __restrict__ psum,
                                                 unsigned* __restrict__ pmax) {
    __shared__ __align__(16) unsigned short sA[BM][BK + LPAD];
    __shared__ __align__(16) unsigned short sB[BN][BK + LPAD];
    __shared__ int      sLab[BM];
    __shared__ float    sSum[BM];
    __shared__ unsigned sMax[BM];
    __shared__ float    sInvN[BN];

    const int tid = threadIdx.x;
    const int m0 = blockIdx.x * BM;
    const int n0 = blockIdx.y * BN;
    if (tid < BM) { sLab[tid] = label[m0 + tid]; sSum[tid] = 0.f; sMax[tid] = 0u; }

    const int lane = tid & 63;
    const int wave = tid >> 6;
    const int wm = wave >> 1, wn = wave & 1;
    const int q = lane >> 4, lm = lane & 15;

    const int arow = tid >> 3, ac8 = tid & 7;
    const int brow = tid >> 4, bc4 = tid & 15;

    f32x4 acc[4][4];
#pragma unroll
    for (int i = 0; i < 4; ++i)
#pragma unroll
        for (int j = 0; j < 4; ++j) acc[i][j] = (f32x4){0.f, 0.f, 0.f, 0.f};

    float rss[8];
#pragma unroll
    for (int j = 0; j < 8; ++j) rss[j] = 0.f;

    const float* wb = W + (size_t)(n0 + brow) * E_DIM + bc4 * 4;

    for (int k0 = 0; k0 < E_DIM; k0 += BK) {
        __syncthreads();
#pragma unroll
        for (int j = 0; j < 4; ++j) {
            int rr = arow + 32 * j;
            uint4 v = *(const uint4*)(embn + (size_t)(m0 + rr) * E_DIM + k0 + ac8 * 8);
            *(uint4*)(&sA[rr][ac8 * 8]) = v;
        }
#pragma unroll
        for (int j = 0; j < 8; ++j) {
            int rr = brow + 16 * j;
            f32x4 v = (f32x4){0.f, 0.f, 0.f, 0.f};
            if (n0 + rr < C_CLS) v = *(const f32x4*)(wb + (size_t)(16 * j) * E_DIM + k0);
            rss[j] += v.x * v.x + v.y * v.y + v.z * v.z + v.w * v.w;
            ushort4 o; o.x = f2bf(v.x); o.y = f2bf(v.y); o.z = f2bf(v.z); o.w = f2bf(v.w);
            *(ushort4*)(&sB[rr][bc4 * 4]) = o;
        }
        __syncthreads();
#pragma unroll
        for (int kk = 0; kk < BK; kk += 32) {
            bf16x8 af[4], bfr[4];
#pragma unroll
            for (int i = 0; i < 4; ++i)
                af[i] = *(const bf16x8*)(&sA[wm * 64 + i * 16 + lm][kk + q * 8]);
#pragma unroll
            for (int j = 0; j < 4; ++j)
                bfr[j] = *(const bf16x8*)(&sB[wn * 64 + j * 16 + lm][kk + q * 8]);
#pragma unroll
            for (int i = 0; i < 4; ++i)
#pragma unroll
                for (int j = 0; j < 4; ++j)
                    acc[i][j] = __builtin_amdgcn_mfma_f32_16x16x32_bf16(af[i], bfr[j], acc[i][j], 0, 0, 0);
        }
    }
#pragma unroll
    for (int j = 0; j < 8; ++j) {
        float v = rss[j];
#pragma unroll
        for (int d = 1; d < 16; d <<= 1) v += __shfl_xor(v, d, 64);
        if (bc4 == 0) sInvN[brow + 16 * j] = rsqrtf(fmaxf(v, 1e-30f));
    }
    __syncthreads();
#pragma unroll
    for (int i = 0; i < 4; ++i) {
#pragma unroll
        for (int r = 0; r < 4; ++r) {
            int row_l = wm * 64 + i * 16 + q * 4 + r;
            int lab = sLab[row_l];
            float sum = 0.f, mx = -1e30f;
#pragma unroll
            for (int j = 0; j < 4; ++j) {
                int col_l = wn * 64 + j * 16 + lm;
                int col = n0 + col_l;
                float v = S_SC * acc[i][j][r] * sInvN[col_l];
                if (col < C_CLS && col != lab) {
                    sum += __expf(v - 30.0f);
                    mx = fmaxf(mx, v);
                }
            }
#pragma unroll
            for (int d = 1; d < 16; d <<= 1) {
                sum += __shfl_xor(sum, d, 64);
                mx = fmaxf(mx, __shfl_xor(mx, d, 64));
            }
            if (lm == 0) {
                atomicAdd(&sSum[row_l], sum);
                atomicMax(&sMax[row_l], fkey(mx));
            }
        }
    }
    __syncthreads();
    if (tid < BM) {
        psum[(size_t)blockIdx.y * B_ROWS + m0 + tid] = sSum[tid];
        pmax[(size_t)blockIdx.y * B_ROWS + m0 + tid] = sMax[tid];
    }
}

// fixed-order reduction over the 782 tile-partials per row (deterministic)
__global__ __launch_bounds__(256) void row_reduce(const float* __restrict__ psum,
                                                  const unsigned* __restrict__ pmax,
                                                  float* __restrict__ rsum,
                                                  float* __restrict__ rmax) {
    __shared__ float s4[4];
    __shared__ unsigned m4[4];
    int b = blockIdx.x, t = threadIdx.x;
    float s = 0.f; unsigned mk = 0u;
    for (int nt = t; nt < NT; nt += 256) {
        s += psum[(size_t)nt * B_ROWS + b];
        unsigned k = pmax[(size_t)nt * B_ROWS + b];
        mk = k > mk ? k : mk;
    }
    s = waveReduceSum(s);
    mk = waveReduceMax(mk);
    int w = t >> 6;
    if ((t & 63) == 0) { s4[w] = s; m4[w] = mk; }
    __syncthreads();
    if (t == 0) {
        rsum[b] = s4[0] + s4[1] + s4[2] + s4[3];
        unsigned m = m4[0];
#pragma unroll
        for (int i = 1; i < 4; ++i) m = m4[i] > m ? m4[i] : m;
        rmax[b] = unkey(m);
    }
}

__global__ __launch_bounds__(256) void finalize(const float* __restrict__ cosl,
                                                const float* __restrict__ rsum,
                                                const float* __restrict__ rmax,
                                                const float* __restrict__ closs,
                                                float* __restrict__ out) {
    __shared__ float s4[4];
    int t = threadIdx.x;
    float lsum = 0.f, msum = 0.f;
    for (int b = t; b < B_ROWS; b += 256) {
        float lv = S_SC * (cosl[b] - M_MRG);
        float tot = rsum[b] + __expf(lv - 30.0f);
        lsum += (logf(tot) + 30.0f) - lv;
        msum += (lv > rmax[b]) ? 1.0f : 0.0f;
    }
    lsum = blockReduceSum256(lsum, s4);
    msum = blockReduceSum256(msum, s4);
    if (t == 0) {
        out[0] = msum * (100.0f / (float)B_ROWS);
        out[1] = lsum * (1.0f / (float)B_ROWS)
               + LAMBDA_ * closs[0] * (1.0f / ((float)B_ROWS * (float)E_DIM));
    }
}

// new_centers = centers (dst is only 8B-aligned -> float2)
__global__ __launch_bounds__(256) void centers_copy(const float* __restrict__ src,
                                                    float* __restrict__ dst) {
    size_t i = (size_t)blockIdx.x * blockDim.x + threadIdx.x;
    size_t stride = (size_t)gridDim.x * blockDim.x;
    size_t n2 = (size_t)C_CLS * E_DIM / 2;
    const float2* s2 = (const float2*)src;
    float2* d2 = (float2*)dst;
    for (size_t k = i; k < n2; k += stride) d2[k] = s2[k];
}

// scatter: new_centers[label[b]] += alpha*(e - c)/(count+eps)
__global__ __launch_bounds__(256) void scatter_upd(const float* __restrict__ emb,
                                                   const float* __restrict__ centers,
                                                   const int* __restrict__ label,
                                                   const float* __restrict__ cntf,
                                                   float* __restrict__ outC) {
    int b = blockIdx.x, t = threadIdx.x;
    int lab = label[b];
    float sc = ALPHA_ / (cntf[b] + EPS_);
    for (int c = t; c < E_DIM; c += 256) {
        float add = sc * (emb[(size_t)b * E_DIM + c] - centers[(size_t)lab * E_DIM + c]);
        atomicAdd(outC + (size_t)lab * E_DIM + c, add);
    }
}

// ---------------- launcher ----------------
extern "C" void kernel_launch(void* const* d_in, const int* in_sizes, int n_in,
                              void* d_out, int out_size, void* d_ws, size_t ws_size,
                              hipStream_t stream) {
    const float* emb     = (const float*)d_in[0];
    const float* W       = (const float*)d_in[1];
    const float* centers = (const float*)d_in[2];
    const int*   label   = (const int*)d_in[3];
    float* out = (float*)d_out;
    char* ws = (char*)d_ws;

    float*          psum = (float*)(ws + WS_PSUM);
    unsigned*       pmax = (unsigned*)(ws + WS_PMAX);
    float*          closs = (float*)(ws + WS_CLOSS);
    unsigned short* embn = (unsigned short*)(ws + WS_EMBN);
    float*          ien  = (float*)(ws + WS_IEN);
    float*          cosl = (float*)(ws + WS_COSL);
    float*          cntf = (float*)(ws + WS_CNT);
    float*          rsum = (float*)(ws + WS_RSUM);
    float*          rmax = (float*)(ws + WS_RMAX);
    unsigned short* wbf  = (unsigned short*)(ws + WS_WBF);

    hipMemsetAsync(ws + WS_CLOSS, 0, 512, stream);

    emb_prep<<<B_ROWS, 256, 0, stream>>>(emb, embn, ien);
    label_stats<<<B_ROWS, 256, 0, stream>>>(emb, W, centers, label, ien, cosl, cntf, closs);
    if (ws_size >= WS_NEED) {
        w_prep<<<C_CLS / 4, 256, 0, stream>>>(W, wbf);
        gemm_fast<<<NT, 256, 0, stream>>>(embn, wbf, label, psum, pmax);
    } else {
        gemm_slow<<<dim3(B_ROWS / BM, NT), 256, 0, stream>>>(embn, W, label, psum, pmax);
    }
    row_reduce<<<B_ROWS, 256, 0, stream>>>(psum, pmax, rsum, rmax);
    finalize<<<1, 256, 0, stream>>>(cosl, rsum, rmax, closs, out);
    centers_copy<<<12500, 256, 0, stream>>>(centers, out + 2);
    scatter_upd<<<B_ROWS, 256, 0, stream>>>(emb, centers, label, cntf, out + 2);
}